// Round 6
// baseline (23218.768 us; speedup 1.0000x reference)
//
#include <hip/hip_runtime.h>

// ---------------------------------------------------------------------------
// 2-layer ReLU RNN, B=64 T=2048 IN=256 H=512 C=128. fp32 inputs (runtime
// dtype detect kept), output dtype matches input.
//
// Round-11: ELIMINATE the intra-layer sibling exchange (round-10's wall,
// ~2.5-3 us/step of coherence round-trips). Each recurrent row-group
// (16 batch rows x all 512 cols) now lives in ONE 512-thread (8-wave) WG:
//   - h stays in LDS (single 16KB stage, 2 barriers/step). No global
//     round-trip on the recurrent chain at all.
//   - W per wave = 64 cols: j-blocks 0,1 in registers (128 VGPR),
//     j-blocks 2,3 STREAMED from L2 each step (W static, L2-resident,
//     depth-4 register ring hides latency).
// Grid = 16 WGs x 512:
//   bid 0-3  L0    (row-group r): publishes h0 -> hex0 8-ring (feed-forward
//            only; gated by progP, LAG=7).
//   bid 4-7  L1REC (row-group r): h1 = relu(z + Whh1 h1), z prefetched from
//            hexZ; publishes nothing but h_last/carry. progL certifies z use.
//   bid 8-15 PROJ  (r, half): z = Wih1 h0 + b1 over 256 cols, 8 waves x 32
//            cols all-register; publishes pos/neg-split tagged z -> hexZ
//            8-ring (gated by progL, LAG=7).
// Tags: 4-bit step tag (t&15) in the 4 f16 sign bits of each u64; rings
// 8-deep; same alias audit as round-9. All spins guard-limited.
// ---------------------------------------------------------------------------

typedef unsigned short u16;
typedef unsigned int u32;
typedef unsigned long long u64;
typedef _Float16 f16;
typedef _Float16 half8 __attribute__((ext_vector_type(8)));
typedef float float4v __attribute__((ext_vector_type(4)));

#define T_LEN 2048
#define H_DIM 512
#define B_SZ 64
#define SGN 0x8000800080008000ull
#define VMASK 0x7fff7fff7fff7fffull
#define SPIN_LIM (1 << 15)
#define LAG 7

__device__ __forceinline__ float bf2f(u16 u) {
    union { u32 i; float f; } v; v.i = ((u32)u) << 16; return v.f;
}
__device__ __forceinline__ u16 f2bf(float f) {
    u32 x = __float_as_uint(f);
    u32 r = (x + 0x7fffu + ((x >> 16) & 1u)) >> 16;
    return (u16)r;
}
__device__ __forceinline__ float loadf(const void* p, size_t i, int dt) {
    return dt ? ((const float*)p)[i] : bf2f(((const u16*)p)[i]);
}
__device__ __forceinline__ half8 cvt8_bf16(uint4 v) {
    half8 h;
    h[0] = (f16)bf2f((u16)(v.x & 0xffff)); h[1] = (f16)bf2f((u16)(v.x >> 16));
    h[2] = (f16)bf2f((u16)(v.y & 0xffff)); h[3] = (f16)bf2f((u16)(v.y >> 16));
    h[4] = (f16)bf2f((u16)(v.z & 0xffff)); h[5] = (f16)bf2f((u16)(v.z >> 16));
    h[6] = (f16)bf2f((u16)(v.w & 0xffff)); h[7] = (f16)bf2f((u16)(v.w >> 16));
    return h;
}
// 4-bit tag (t & 15) in the 4 f16 sign bits of a u64.
__device__ __forceinline__ u64 tagmask(int t) {
    return ((t & 1) ? 0x0000000000008000ull : 0ull) |
           ((t & 2) ? 0x0000000080000000ull : 0ull) |
           ((t & 4) ? 0x0000800000000000ull : 0ull) |
           ((t & 8) ? 0x8000000000000000ull : 0ull);
}
__device__ __forceinline__ u64 aload(u64* p) {
    return __hip_atomic_load(p, __ATOMIC_RELAXED, __HIP_MEMORY_SCOPE_AGENT);
}
__device__ __forceinline__ void astore(u64* p, u64 v) {
    __hip_atomic_store(p, v, __ATOMIC_RELAXED, __HIP_MEMORY_SCOPE_AGENT);
}
__device__ __forceinline__ u32 aload32(u32* p) {
    return __hip_atomic_load(p, __ATOMIC_RELAXED, __HIP_MEMORY_SCOPE_AGENT);
}
__device__ __forceinline__ void astore32(u32* p, u32 v) {
    __hip_atomic_store(p, v, __ATOMIC_RELAXED, __HIP_MEMORY_SCOPE_AGENT);
}
__device__ __forceinline__ float f16u(u16 b) {
    union { u16 u; f16 h; } c; c.u = b; return (float)c.h;
}
// Validate N in-flight words (indices idx[q] into base) vs tag em.
template<int N>
__device__ __forceinline__ void validateN(u64* base, const int* idx, u64 em, u64* vv) {
    int pend = 0;
#pragma unroll
    for (int q = 0; q < N; ++q)
        if ((vv[q] & SGN) != em) pend |= 1 << q;
    int guard = 0;
    while (pend && guard < SPIN_LIM) {
#pragma unroll
        for (int q = 0; q < N; ++q)
            if (pend & (1 << q)) vv[q] = aload(&base[idx[q]]);
#pragma unroll
        for (int q = 0; q < N; ++q)
            if ((pend & (1 << q)) && ((vv[q] & SGN) == em))
                pend &= ~(1 << q);
        ++guard;
    }
}

// --------------------------- dtype detection -------------------------------
__global__ void detect_kernel(const u16* __restrict__ xr, int* __restrict__ dtf,
                              u32* __restrict__ progP, u32* __restrict__ progL) {
    int lane = threadIdx.x;
    u16 u0 = xr[(lane * 2 + 0) * 2];
    u16 u1 = xr[(lane * 2 + 1) * 2];
    int e0 = (u0 >> 7) & 0xff, e1 = (u1 >> 7) & 0xff;
    int c0 = (e0 >= 0x60 && e0 <= 0x8f) ? 1 : 0;
    int c1 = (e1 >= 0x60 && e1 <= 0x8f) ? 1 : 0;
    int tot = __popcll(__ballot(c0)) + __popcll(__ballot(c1));
    if (lane == 0) *dtf = (tot >= 96) ? 0 : 1;   // 0 = bf16, 1 = fp32
    progP[lane] = 0;
    progL[lane] = 0;
}

// --------------------------- prep kernels ----------------------------------
__global__ void cvt_w_kernel(const void* __restrict__ in, f16* __restrict__ out,
                             int n, const int* __restrict__ dtf) {
    int dt = *dtf;
    for (int i = blockIdx.x * blockDim.x + threadIdx.x; i < n; i += gridDim.x * blockDim.x)
        out[i] = (f16)loadf(in, i, dt);
}

__global__ void bias_kernel(const void* __restrict__ bi, const void* __restrict__ bh,
                            float* __restrict__ bias, const int* __restrict__ dtf) {
    int dt = *dtf;
    int i = blockIdx.x * blockDim.x + threadIdx.x;
    if (i < H_DIM) bias[i] = loadf(bi, i, dt) + loadf(bh, i, dt);
}

__global__ void fcb_kernel(const void* __restrict__ in, float* __restrict__ out,
                           const int* __restrict__ dtf) {
    int i = threadIdx.x;
    if (i < 128) out[i] = loadf(in, i, *dtf);
}

// --------------------------- tiled MFMA GEMM -------------------------------
template<int RAW>
__global__ __launch_bounds__(256)
void gemm_tiled(const void* __restrict__ Araw, const f16* __restrict__ Bw,
                const float* __restrict__ bias, f16* __restrict__ C,
                int lgTc, int t_off, int K, const int* __restrict__ dtf)
{
    __shared__ f16 As[64][40];
    __shared__ f16 Bs[64][40];
    const int dt = RAW ? *dtf : 0;
    const int m0 = blockIdx.x * 64, n0 = blockIdx.y * 64;
    const int tid = threadIdx.x;
    const int wv = tid >> 6, lane = tid & 63;
    const int lr = lane & 15, quad = lane >> 4;
    const int srow = tid >> 2, skq = tid & 3;

    float4v acc[4] = {{0.f,0.f,0.f,0.f},{0.f,0.f,0.f,0.f},{0.f,0.f,0.f,0.f},{0.f,0.f,0.f,0.f}};

    size_t arow;
    {
        int ml = m0 + srow;
        if (RAW) {
            int b = ml >> lgTc, tt = ml & ((1 << lgTc) - 1);
            arow = (size_t)b * T_LEN + t_off + tt;
        } else arow = (size_t)ml;
    }
    const f16* pb = Bw + (size_t)(n0 + srow) * K + skq * 8;

    for (int k0 = 0; k0 < K; k0 += 32) {
        half8 av;
        if (RAW) {
            if (dt) {
                const float* ap = (const float*)Araw + arow * K + k0 + skq * 8;
                float4v f0 = *(const float4v*)ap;
                float4v f1 = *(const float4v*)(ap + 4);
                av[0]=(f16)f0[0]; av[1]=(f16)f0[1]; av[2]=(f16)f0[2]; av[3]=(f16)f0[3];
                av[4]=(f16)f1[0]; av[5]=(f16)f1[1]; av[6]=(f16)f1[2]; av[7]=(f16)f1[3];
            } else {
                av = cvt8_bf16(*(const uint4*)((const u16*)Araw + arow * K + k0 + skq * 8));
            }
        } else {
            av = *(const half8*)((const f16*)Araw + arow * K + k0 + skq * 8);
        }
        half8 bv = *(const half8*)(pb + k0);
        __syncthreads();
        *(half8*)&As[srow][skq * 8] = av;
        *(half8*)&Bs[srow][skq * 8] = bv;
        __syncthreads();
        half8 bf = *(const half8*)&Bs[wv * 16 + lr][quad * 8];
#pragma unroll
        for (int mt = 0; mt < 4; ++mt) {
            half8 af = *(const half8*)&As[mt * 16 + lr][quad * 8];
            acc[mt] = __builtin_amdgcn_mfma_f32_16x16x32_f16(af, bf, acc[mt], 0, 0, 0);
        }
    }
    const int n = n0 + wv * 16 + lr;
    const float bval = bias[n];
#pragma unroll
    for (int mt = 0; mt < 4; ++mt) {
#pragma unroll
        for (int i = 0; i < 4; ++i) {
            int m = m0 + mt * 16 + quad * 4 + i;
            C[(size_t)m * H_DIM + n] = (f16)(acc[mt][i] + bval);
        }
    }
}

// --------------------------- 3-role scan, self-contained WGs ---------------
// grid = 16 x 512 threads (8 waves).
// bid 0-3:  L0    r=bid       16 rows x 512 cols, h in LDS.
// bid 4-7:  L1REC r=bid-4     same, input z from hexZ.
// bid 8-15: PROJ  r=(bid-8)>>1, half=(bid-8)&1  (256 cols).
// hex0 [8][64][128] u64, hexZ [8][4][2][2048] u64 (pos 1024 ++ neg 1024).
// progP[r*2+half]: PROJ consumed h0_t -> t+1. progL[r]: L1REC consumed z_t.
__global__ __launch_bounds__(512, 2)
void rnn_scan3(const f16* __restrict__ pre0,    // [B,Tc,H] chunk-local
               const f16* __restrict__ Whh0,    // [H,H] fp16
               const f16* __restrict__ Wih1,    // [H,H] fp16
               const f16* __restrict__ Whh1,    // [H,H] fp16
               const float* __restrict__ bias1, // [H] fp32
               u64* __restrict__ hex0,          // [8][64][128]
               u64* __restrict__ hexZ,          // [8][4][2][2048]
               f16* __restrict__ hc0,           // [B,H] layer-0 carry
               f16* __restrict__ hc1,           // [B,H] layer-1 carry
               u32* __restrict__ progP,         // [8]
               u32* __restrict__ progL,         // [4]
               int t0, int Tc,
               float* __restrict__ h_last)      // [B,H] fp32
{
    __shared__ f16 stage[16 * 512];   // L0/L1REC h (granule-XOR swizzle)
    __shared__ f16 sH0[16 * 512];     // PROJ h0 staging
    const int bid = blockIdx.x;
    const int tid = threadIdx.x;
    const int w = tid >> 6, lane = tid & 63;
    const int lr = lane & 15, quad = lane >> 4;

    if (bid >= 8) {
        // ============================ PROJ ============================
        const int r = (bid - 8) >> 1, half = (bid - 8) & 1;
        const int rows0 = r * 16;
        const int c0p = half * 256 + w * 32;
        half8 Bf[2][16];
#pragma unroll
        for (int j = 0; j < 2; ++j)
#pragma unroll
            for (int kc = 0; kc < 16; ++kc)
                Bf[j][kc] = *(const half8*)(Wih1 + (size_t)(c0p + j * 16 + lr) * H_DIM
                                            + kc * 32 + quad * 8);
        float bvv[2] = { bias1[c0p + lr], bias1[c0p + 16 + lr] };
        const int rrow = tid >> 5;               // 16 rows x 32 thr
        const int rc4 = (tid & 31) * 4;          // 4 u64-cols per thread
        int hidx[4];
#pragma unroll
        for (int q = 0; q < 4; ++q) hidx[q] = rc4 + q;
        const int lc0 = w * 32 + lr, lc1 = lc0 + 16;

        u64 vv[4];
        {
            u64* src = hex0 + ((size_t)(t0 & 7) * 64 + rows0 + rrow) * 128;
#pragma unroll
            for (int q = 0; q < 4; ++q) vv[q] = aload(&src[hidx[q]]);
        }

        for (int tt = 0; tt < Tc; ++tt) {
            const int t = t0 + tt;
            const int nb = t & 7;
            const u64 em = tagmask(t);
            const int need = t - LAG;
            const u32 want = (u32)(need + 1);

            u32 plv = 0xffffffffu;
            if (need >= 0) plv = aload32(&progL[r]);   // early poll

            // validate h0_t -> sH0
            {
                u64* src = hex0 + ((size_t)nb * 64 + rows0 + rrow) * 128;
                validateN<4>(src, hidx, em, vv);
#pragma unroll
                for (int q = 0; q < 4; ++q) {
                    int cu = rc4 + q;
                    *(u64*)&sH0[rrow * 512 + ((cu >> 1) ^ (rrow & 7)) * 8 + (cu & 1) * 4] =
                        vv[q] & VMASK;
                }
            }
            __syncthreads();   // sH0 ready; all hex0[t] reads done
            if (tid == 0) astore32(&progP[r * 2 + half], (u32)(t + 1));

            float4v acc0 = {0.f,0.f,0.f,0.f}, acc1 = {0.f,0.f,0.f,0.f};
#pragma unroll
            for (int kc = 0; kc < 16; ++kc) {
                half8 a = *(const half8*)&sH0[lr * 512 + (((kc * 4 + quad) ^ (lr & 7)) * 8)];
                acc0 = __builtin_amdgcn_mfma_f32_16x16x32_f16(a, Bf[0][kc], acc0, 0, 0, 0);
                acc1 = __builtin_amdgcn_mfma_f32_16x16x32_f16(a, Bf[1][kc], acc1, 0, 0, 0);
            }

            // pack z = acc + bias as pos/neg col-major u64 (4 rows per u64)
            u64 zw[4];
#pragma unroll
            for (int j = 0; j < 2; ++j) {
                const float4v& a = j ? acc1 : acc0;
                u64 wp = 0, wn = 0;
#pragma unroll
                for (int i = 0; i < 4; ++i) {
                    float z = a[i] + bvv[j];
                    union { f16 h; u16 u; } cp, cn;
                    cp.h = (f16)fmaxf(z, 0.f);
                    cn.h = (f16)fmaxf(-z, 0.f);
                    wp |= ((u64)cp.u) << (16 * i);
                    wn |= ((u64)cn.u) << (16 * i);
                }
                zw[j] = wp; zw[2 + j] = wn;
            }

            // throttle: publishing z_t destroys z_{t-8}; progL >= t-6 ok.
            if (need >= 0) {
                int g = 0;
                while (plv < want && g < SPIN_LIM) { plv = aload32(&progL[r]); ++g; }
            }

            {
                u64* dz = hexZ + (((size_t)nb * 4 + r) * 2 + half) * 2048;
                astore(&dz[lc0 * 4 + quad],        zw[0] | em);
                astore(&dz[lc1 * 4 + quad],        zw[1] | em);
                astore(&dz[1024 + lc0 * 4 + quad], zw[2] | em);
                astore(&dz[1024 + lc1 * 4 + quad], zw[3] | em);
            }
            if (tt + 1 < Tc) {
                u64* srcn = hex0 + ((size_t)((t + 1) & 7) * 64 + rows0 + rrow) * 128;
#pragma unroll
                for (int q = 0; q < 4; ++q) vv[q] = aload(&srcn[hidx[q]]);
            }
            __syncthreads();   // protect sH0 rewrite next iteration
        }
        return;
    }

    // ========================= L0 / L1REC =========================
    const int role = bid >> 2;            // 0 = L0, 1 = L1REC
    const int r = bid & 3;
    const int rows0 = r * 16;
    const int c0w = w * 64;               // wave's 64 output cols
    const f16* Wrec = role ? Whh1 : Whh0;
    f16* hcar = role ? hc1 : hc0;

    half8 Bf[2][16];                      // j = 0,1 in registers
#pragma unroll
    for (int j = 0; j < 2; ++j)
#pragma unroll
        for (int kc = 0; kc < 16; ++kc)
            Bf[j][kc] = *(const half8*)(Wrec + (size_t)(c0w + j * 16 + lr) * H_DIM
                                        + kc * 32 + quad * 8);
    const f16* Wg2 = Wrec + (size_t)(c0w + 32 + lr) * H_DIM + quad * 8;  // j=2 streamed
    const f16* Wg3 = Wrec + (size_t)(c0w + 48 + lr) * H_DIM + quad * 8;  // j=3 streamed

    if (t0 > 0) {
        int row = tid >> 5, g0 = (tid & 31) * 2;
#pragma unroll
        for (int gq = 0; gq < 2; ++gq) {
            int g = g0 + gq;
            *(uint4*)&stage[row * 512 + ((g ^ (row & 7)) * 8)] =
                *(const uint4*)(hcar + (size_t)(rows0 + row) * H_DIM + g * 8);
        }
    }
    __syncthreads();

    // L1REC z prefetch state
    u64 vvz[8];
    int zidx[8];
    const int halfW = w >> 2, lcw = (w & 3) * 64;
    if (role) {
#pragma unroll
        for (int j = 0; j < 4; ++j) {
            zidx[j] = (lcw + j * 16 + lr) * 4 + quad;
            zidx[4 + j] = 1024 + zidx[j];
        }
        u64* zb = hexZ + (((size_t)(t0 & 7) * 4 + r) * 2 + halfW) * 2048;
#pragma unroll
        for (int q = 0; q < 8; ++q) vvz[q] = aload(&zb[zidx[q]]);
    }

    float pv[4][4];
    if (!role) {
#pragma unroll
        for (int j = 0; j < 4; ++j)
#pragma unroll
            for (int i = 0; i < 4; ++i)
                pv[j][i] = (float)pre0[((size_t)(rows0 + quad * 4 + i) * Tc + 0) * H_DIM
                                       + c0w + j * 16 + lr];
    }

    const int prow = tid >> 5, pc4 = (tid & 31) * 4;   // L0 publish mapping

    for (int tt = 0; tt < Tc; ++tt) {
        const int t = t0 + tt;
        const int nb = t & 7;
        const u64 em = tagmask(t);
        const int need = t - LAG;
        const u32 want = (u32)(need + 1);

        u32 ppv = 0xffffffffu;
        if (!role && need >= 0 && lane < 2)
            ppv = aload32(&progP[r * 2 + lane]);       // early poll

        // MFMA: h_{t-1} (stage) x [Bf | streamed Wg2/Wg3]
        float4v acc[4] = {{0.f,0.f,0.f,0.f},{0.f,0.f,0.f,0.f},
                          {0.f,0.f,0.f,0.f},{0.f,0.f,0.f,0.f}};
        if (t > 0) {
            half8 w2[4], w3[4];
#pragma unroll
            for (int kk = 0; kk < 4; ++kk) {
                w2[kk] = *(const half8*)(Wg2 + kk * 32);
                w3[kk] = *(const half8*)(Wg3 + kk * 32);
            }
#pragma unroll
            for (int kc = 0; kc < 16; ++kc) {
                half8 a = *(const half8*)&stage[lr * 512 + (((kc * 4 + quad) ^ (lr & 7)) * 8)];
                acc[0] = __builtin_amdgcn_mfma_f32_16x16x32_f16(a, Bf[0][kc], acc[0], 0, 0, 0);
                acc[1] = __builtin_amdgcn_mfma_f32_16x16x32_f16(a, Bf[1][kc], acc[1], 0, 0, 0);
                acc[2] = __builtin_amdgcn_mfma_f32_16x16x32_f16(a, w2[kc & 3], acc[2], 0, 0, 0);
                acc[3] = __builtin_amdgcn_mfma_f32_16x16x32_f16(a, w3[kc & 3], acc[3], 0, 0, 0);
                if (kc < 12) {
                    w2[kc & 3] = *(const half8*)(Wg2 + (kc + 4) * 32);
                    w3[kc & 3] = *(const half8*)(Wg3 + (kc + 4) * 32);
                }
            }
        }

        // L1REC: validate z_t, unpack to pv.
        if (role) {
            u64* zb = hexZ + (((size_t)nb * 4 + r) * 2 + halfW) * 2048;
            validateN<8>(zb, zidx, em, vvz);
#pragma unroll
            for (int j = 0; j < 4; ++j) {
                u64 pw = vvz[j] & VMASK, nw = vvz[4 + j] & VMASK;
#pragma unroll
                for (int i = 0; i < 4; ++i)
                    pv[j][i] = f16u((u16)(pw >> (16 * i))) - f16u((u16)(nw >> (16 * i)));
            }
        }
        __syncthreads();   // all stage reads + z validates done
        if (role && tid == 0) astore32(&progL[r], (u32)(t + 1));

        // h_t = relu(acc + pv) -> stage
        f16 hv[4][4];
#pragma unroll
        for (int j = 0; j < 4; ++j)
#pragma unroll
            for (int i = 0; i < 4; ++i) {
                float hval = fmaxf(acc[j][i] + pv[j][i], 0.f);
                hv[j][i] = (f16)hval;
                int row = quad * 4 + i, lc = c0w + j * 16 + lr;
                stage[row * 512 + ((lc >> 3) ^ (row & 7)) * 8 + (lc & 7)] = hv[j][i];
            }
        if (role && h_last && t == T_LEN - 1) {
#pragma unroll
            for (int j = 0; j < 4; ++j)
#pragma unroll
                for (int i = 0; i < 4; ++i)
                    h_last[(size_t)(rows0 + quad * 4 + i) * H_DIM + c0w + j * 16 + lr] =
                        (float)hv[j][i];
        }
        if (tt == Tc - 1) {
#pragma unroll
            for (int j = 0; j < 4; ++j)
#pragma unroll
                for (int i = 0; i < 4; ++i)
                    hcar[(size_t)(rows0 + quad * 4 + i) * H_DIM + c0w + j * 16 + lr] =
                        hv[j][i];
        }
        __syncthreads();   // stage (h_t) complete

        if (!role) {
            // throttle: publishing h0_t destroys slot t-8; progP >= t-6 ok.
            if (need >= 0) {
                bool ok = __all((lane < 2) ? (ppv >= want) : 1);
                int g = 0;
                while (!ok && g < SPIN_LIM) {
                    if (lane < 2) ppv = aload32(&progP[r * 2 + lane]);
                    ok = __all((lane < 2) ? (ppv >= want) : 1);
                    ++g;
                }
            }
            // publish h0_t (4 u64/thread, row-major) -> hex0
            u64* dst = hex0 + ((size_t)nb * 64 + rows0 + prow) * 128;
#pragma unroll
            for (int q = 0; q < 4; ++q) {
                int cu = pc4 + q;
                u64 v = *(const u64*)&stage[prow * 512 + ((cu >> 1) ^ (prow & 7)) * 8
                                            + (cu & 1) * 4];
                astore(&dst[cu], v | em);
            }
            // pv prefetch for t+1
            if (tt + 1 < Tc) {
#pragma unroll
                for (int j = 0; j < 4; ++j)
#pragma unroll
                    for (int i = 0; i < 4; ++i)
                        pv[j][i] = (float)pre0[((size_t)(rows0 + quad * 4 + i) * Tc + tt + 1)
                                               * H_DIM + c0w + j * 16 + lr];
            }
        } else {
            // z prefetch for t+1
            if (tt + 1 < Tc) {
                u64* zb = hexZ + (((size_t)((t + 1) & 7) * 4 + r) * 2 + halfW) * 2048;
#pragma unroll
                for (int q = 0; q < 8; ++q) vvz[q] = aload(&zb[zidx[q]]);
            }
        }
    }
}

// --------------------------- final FC --------------------------------------
__global__ void fc_kernel(const float* __restrict__ hlast, const f16* __restrict__ fcw,
                          const float* __restrict__ fcb, void* __restrict__ out,
                          const int* __restrict__ dtf) {
    int b = blockIdx.x, c = threadIdx.x;
    const float* hrow = hlast + b * H_DIM;
    const f16* wrow = fcw + (size_t)c * H_DIM;
    float s = fcb[c];
    for (int h0 = 0; h0 < H_DIM; h0 += 8) {
        half8 w = *(const half8*)(wrow + h0);
#pragma unroll
        for (int j = 0; j < 8; ++j) s += hrow[h0 + j] * (float)w[j];
    }
    if (*dtf) ((float*)out)[b * 128 + c] = s;
    else      ((u16*)out)[b * 128 + c] = f2bf(s);
}

// --------------------------- launch ----------------------------------------
extern "C" void kernel_launch(void* const* d_in, const int* in_sizes, int n_in,
                              void* d_out, int out_size, void* d_ws, size_t ws_size,
                              hipStream_t stream)
{
    const void* x     = d_in[0];
    const void* W_ih0 = d_in[1];
    const void* W_hh0 = d_in[2];
    const void* b_ih0 = d_in[3];
    const void* b_hh0 = d_in[4];
    const void* W_ih1 = d_in[5];
    const void* W_hh1 = d_in[6];
    const void* b_ih1 = d_in[7];
    const void* b_hh1 = d_in[8];
    const void* fc_w  = d_in[9];
    const void* fc_b  = d_in[10];

    char* ws = (char*)d_ws;
    int*   dtf   = (int*)(ws + 0);            //     64 B
    float* bias0 = (float*)(ws + 4096);       //   2048 B
    float* bias1 = (float*)(ws + 6144);       //   2048 B
    float* fcbf  = (float*)(ws + 8192);       //    512 B
    u32*   progP = (u32*)(ws + 12288);        //    256 B
    u32*   progL = (u32*)(ws + 12544);        //    256 B
    float* hlast = (float*)(ws + 16384);      // 131072 B
    f16*   hc0   = (f16*)(ws + 147456);       //  65536 B
    f16*   hc1   = (f16*)(ws + 212992);       //  65536 B
    u64*   hex0  = (u64*)(ws + 278528);       // 524288 B [8][64][128]
    u64*   hexZ  = (u64*)(ws + 802816);       // 1048576 B [8][4][2][2048]
    f16*   Wih0f = (f16*)(ws + 1851392);      // 262144 B
    f16*   Whh0f = (f16*)(ws + 2113536);      // 524288 B
    f16*   Wih1f = (f16*)(ws + 2637824);      // 524288 B
    f16*   Whh1f = (f16*)(ws + 3162112);      // 524288 B
    f16*   fcwf  = (f16*)(ws + 3686400);      // 131072 B (ends 3817472 < 4MB)

    const size_t misc = 4u << 20;
    int Tc = 128;
    {
        auto need = [&](int tc) {
            return misc + (size_t)B_SZ * (size_t)tc * H_DIM * 2;
        };
        if (ws_size >= need(2048)) Tc = 2048;
        else if (ws_size >= need(1024)) Tc = 1024;
        else if (ws_size >= need(512)) Tc = 512;
        else if (ws_size >= need(256)) Tc = 256;
        else Tc = 128;
    }
    int lgTc = 31 - __builtin_clz((unsigned)Tc);
    f16* bufA = (f16*)(ws + misc);

    detect_kernel<<<dim3(1), dim3(64), 0, stream>>>((const u16*)x, dtf, progP, progL);
    cvt_w_kernel<<<dim3(512), dim3(256), 0, stream>>>(W_ih0, Wih0f, H_DIM * 256, dtf);
    cvt_w_kernel<<<dim3(1024), dim3(256), 0, stream>>>(W_hh0, Whh0f, H_DIM * H_DIM, dtf);
    cvt_w_kernel<<<dim3(1024), dim3(256), 0, stream>>>(W_ih1, Wih1f, H_DIM * H_DIM, dtf);
    cvt_w_kernel<<<dim3(1024), dim3(256), 0, stream>>>(W_hh1, Whh1f, H_DIM * H_DIM, dtf);
    cvt_w_kernel<<<dim3(256), dim3(256), 0, stream>>>(fc_w, fcwf, 128 * H_DIM, dtf);
    bias_kernel<<<dim3(2), dim3(256), 0, stream>>>(b_ih0, b_hh0, bias0, dtf);
    bias_kernel<<<dim3(2), dim3(256), 0, stream>>>(b_ih1, b_hh1, bias1, dtf);
    fcb_kernel<<<dim3(1), dim3(128), 0, stream>>>(fc_b, fcbf, dtf);

    const int NC = T_LEN / Tc;
    const int mblocks = B_SZ * Tc / 64;
    for (int c = 0; c < NC; ++c) {
        const int t0 = c * Tc;
        gemm_tiled<1><<<dim3(mblocks, 8), 256, 0, stream>>>(
            x, Wih0f, bias0, bufA, lgTc, t0, 256, dtf);
        rnn_scan3<<<dim3(16), dim3(512), 0, stream>>>(
            bufA, Whh0f, Wih1f, Whh1f, bias1, hex0, hexZ, hc0, hc1,
            progP, progL, t0, Tc, hlast);
    }
    fc_kernel<<<dim3(B_SZ), dim3(128), 0, stream>>>(hlast, fcwf, fcbf, d_out, dtf);
}

// Round 7
// 18864.044 us; speedup vs baseline: 1.2308x; 1.2308x over previous
//
#include <hip/hip_runtime.h>

// ---------------------------------------------------------------------------
// 2-layer ReLU RNN, B=64 T=2048 IN=256 H=512 C=128. fp32 inputs (runtime
// dtype detect kept), output dtype matches input.
//
// Round-12: round-11's self-contained-WG architecture (one 8-wave WG owns a
// full 16-row x 512-col recurrence; h lives in LDS; NO intra-layer sibling
// exchange) with the two round-11 defects fixed:
//  (1) VGPR budget: __launch_bounds__(512,2) acted as min-2-BLOCKS/CU ->
//      128-VGPR cap -> W spilled to scratch (VGPR_Count=128, 11us/step).
//      Now __launch_bounds__(512,1) -> 256-VGPR cap. W held as 3 j-blocks
//      in registers (Bf[3][16] = 192 VGPR).
//  (2) No per-step L2 W streaming: the 4th j-block (128 cols x 512 = 128KB)
//      sits in LDS (granule-XOR swizzled), filled ONCE at kernel start.
//      Per-step W traffic = 16KB/wave from LDS (~0.2us), 2-deep prefetched.
// LDS = 128KB (W) + 16KB (h stage / PROJ sH0) = 144KB <= 160KB, 1 WG/CU.
// Grid = 16 x 512:
//   bid 0-3  L0    r=bid:   h0 scan; publishes h0 -> hex0 8-ring (gated by
//            progP, LAG=7; PROJ is the only consumer).
//   bid 4-7  L1REC r=bid-4: h1 = relu(z + Whh1 h1); z prefetched from hexZ.
//   bid 8-15 PROJ  (r,half): z = Wih1 h0 + b1 (256 cols, W all-register);
//            publishes pos/neg-split tagged z -> hexZ 8-ring (gated progL).
// Tags: 4-bit step tag (t&15) in the 4 f16 sign bits of each u64; rings
// 8-deep; alias audit as round-9. All spins guard-limited -> no hangs.
// ---------------------------------------------------------------------------

typedef unsigned short u16;
typedef unsigned int u32;
typedef unsigned long long u64;
typedef _Float16 f16;
typedef _Float16 half8 __attribute__((ext_vector_type(8)));
typedef float float4v __attribute__((ext_vector_type(4)));

#define T_LEN 2048
#define H_DIM 512
#define B_SZ 64
#define SGN 0x8000800080008000ull
#define VMASK 0x7fff7fff7fff7fffull
#define SPIN_LIM (1 << 15)
#define LAG 7

__device__ __forceinline__ float bf2f(u16 u) {
    union { u32 i; float f; } v; v.i = ((u32)u) << 16; return v.f;
}
__device__ __forceinline__ u16 f2bf(float f) {
    u32 x = __float_as_uint(f);
    u32 r = (x + 0x7fffu + ((x >> 16) & 1u)) >> 16;
    return (u16)r;
}
__device__ __forceinline__ float loadf(const void* p, size_t i, int dt) {
    return dt ? ((const float*)p)[i] : bf2f(((const u16*)p)[i]);
}
__device__ __forceinline__ half8 cvt8_bf16(uint4 v) {
    half8 h;
    h[0] = (f16)bf2f((u16)(v.x & 0xffff)); h[1] = (f16)bf2f((u16)(v.x >> 16));
    h[2] = (f16)bf2f((u16)(v.y & 0xffff)); h[3] = (f16)bf2f((u16)(v.y >> 16));
    h[4] = (f16)bf2f((u16)(v.z & 0xffff)); h[5] = (f16)bf2f((u16)(v.z >> 16));
    h[6] = (f16)bf2f((u16)(v.w & 0xffff)); h[7] = (f16)bf2f((u16)(v.w >> 16));
    return h;
}
// 4-bit tag (t & 15) in the 4 f16 sign bits of a u64.
__device__ __forceinline__ u64 tagmask(int t) {
    return ((t & 1) ? 0x0000000000008000ull : 0ull) |
           ((t & 2) ? 0x0000000080000000ull : 0ull) |
           ((t & 4) ? 0x0000800000000000ull : 0ull) |
           ((t & 8) ? 0x8000000000000000ull : 0ull);
}
__device__ __forceinline__ u64 aload(u64* p) {
    return __hip_atomic_load(p, __ATOMIC_RELAXED, __HIP_MEMORY_SCOPE_AGENT);
}
__device__ __forceinline__ void astore(u64* p, u64 v) {
    __hip_atomic_store(p, v, __ATOMIC_RELAXED, __HIP_MEMORY_SCOPE_AGENT);
}
__device__ __forceinline__ u32 aload32(u32* p) {
    return __hip_atomic_load(p, __ATOMIC_RELAXED, __HIP_MEMORY_SCOPE_AGENT);
}
__device__ __forceinline__ void astore32(u32* p, u32 v) {
    __hip_atomic_store(p, v, __ATOMIC_RELAXED, __HIP_MEMORY_SCOPE_AGENT);
}
__device__ __forceinline__ float f16u(u16 b) {
    union { u16 u; f16 h; } c; c.u = b; return (float)c.h;
}
// Validate N in-flight words (indices idx[q] into base) vs tag em.
template<int N>
__device__ __forceinline__ void validateN(u64* base, const int* idx, u64 em, u64* vv) {
    int pend = 0;
#pragma unroll
    for (int q = 0; q < N; ++q)
        if ((vv[q] & SGN) != em) pend |= 1 << q;
    int guard = 0;
    while (pend && guard < SPIN_LIM) {
#pragma unroll
        for (int q = 0; q < N; ++q)
            if (pend & (1 << q)) vv[q] = aload(&base[idx[q]]);
#pragma unroll
        for (int q = 0; q < N; ++q)
            if ((pend & (1 << q)) && ((vv[q] & SGN) == em))
                pend &= ~(1 << q);
        ++guard;
    }
}

// --------------------------- dtype detection -------------------------------
__global__ void detect_kernel(const u16* __restrict__ xr, int* __restrict__ dtf,
                              u32* __restrict__ progP, u32* __restrict__ progL) {
    int lane = threadIdx.x;
    u16 u0 = xr[(lane * 2 + 0) * 2];
    u16 u1 = xr[(lane * 2 + 1) * 2];
    int e0 = (u0 >> 7) & 0xff, e1 = (u1 >> 7) & 0xff;
    int c0 = (e0 >= 0x60 && e0 <= 0x8f) ? 1 : 0;
    int c1 = (e1 >= 0x60 && e1 <= 0x8f) ? 1 : 0;
    int tot = __popcll(__ballot(c0)) + __popcll(__ballot(c1));
    if (lane == 0) *dtf = (tot >= 96) ? 0 : 1;   // 0 = bf16, 1 = fp32
    progP[lane] = 0;
    progL[lane] = 0;
}

// --------------------------- prep kernels ----------------------------------
__global__ void cvt_w_kernel(const void* __restrict__ in, f16* __restrict__ out,
                             int n, const int* __restrict__ dtf) {
    int dt = *dtf;
    for (int i = blockIdx.x * blockDim.x + threadIdx.x; i < n; i += gridDim.x * blockDim.x)
        out[i] = (f16)loadf(in, i, dt);
}

__global__ void bias_kernel(const void* __restrict__ bi, const void* __restrict__ bh,
                            float* __restrict__ bias, const int* __restrict__ dtf) {
    int dt = *dtf;
    int i = blockIdx.x * blockDim.x + threadIdx.x;
    if (i < H_DIM) bias[i] = loadf(bi, i, dt) + loadf(bh, i, dt);
}

__global__ void fcb_kernel(const void* __restrict__ in, float* __restrict__ out,
                           const int* __restrict__ dtf) {
    int i = threadIdx.x;
    if (i < 128) out[i] = loadf(in, i, *dtf);
}

// --------------------------- tiled MFMA GEMM -------------------------------
template<int RAW>
__global__ __launch_bounds__(256)
void gemm_tiled(const void* __restrict__ Araw, const f16* __restrict__ Bw,
                const float* __restrict__ bias, f16* __restrict__ C,
                int lgTc, int t_off, int K, const int* __restrict__ dtf)
{
    __shared__ f16 As[64][40];
    __shared__ f16 Bs[64][40];
    const int dt = RAW ? *dtf : 0;
    const int m0 = blockIdx.x * 64, n0 = blockIdx.y * 64;
    const int tid = threadIdx.x;
    const int wv = tid >> 6, lane = tid & 63;
    const int lr = lane & 15, quad = lane >> 4;
    const int srow = tid >> 2, skq = tid & 3;

    float4v acc[4] = {{0.f,0.f,0.f,0.f},{0.f,0.f,0.f,0.f},{0.f,0.f,0.f,0.f},{0.f,0.f,0.f,0.f}};

    size_t arow;
    {
        int ml = m0 + srow;
        if (RAW) {
            int b = ml >> lgTc, tt = ml & ((1 << lgTc) - 1);
            arow = (size_t)b * T_LEN + t_off + tt;
        } else arow = (size_t)ml;
    }
    const f16* pb = Bw + (size_t)(n0 + srow) * K + skq * 8;

    for (int k0 = 0; k0 < K; k0 += 32) {
        half8 av;
        if (RAW) {
            if (dt) {
                const float* ap = (const float*)Araw + arow * K + k0 + skq * 8;
                float4v f0 = *(const float4v*)ap;
                float4v f1 = *(const float4v*)(ap + 4);
                av[0]=(f16)f0[0]; av[1]=(f16)f0[1]; av[2]=(f16)f0[2]; av[3]=(f16)f0[3];
                av[4]=(f16)f1[0]; av[5]=(f16)f1[1]; av[6]=(f16)f1[2]; av[7]=(f16)f1[3];
            } else {
                av = cvt8_bf16(*(const uint4*)((const u16*)Araw + arow * K + k0 + skq * 8));
            }
        } else {
            av = *(const half8*)((const f16*)Araw + arow * K + k0 + skq * 8);
        }
        half8 bv = *(const half8*)(pb + k0);
        __syncthreads();
        *(half8*)&As[srow][skq * 8] = av;
        *(half8*)&Bs[srow][skq * 8] = bv;
        __syncthreads();
        half8 bf = *(const half8*)&Bs[wv * 16 + lr][quad * 8];
#pragma unroll
        for (int mt = 0; mt < 4; ++mt) {
            half8 af = *(const half8*)&As[mt * 16 + lr][quad * 8];
            acc[mt] = __builtin_amdgcn_mfma_f32_16x16x32_f16(af, bf, acc[mt], 0, 0, 0);
        }
    }
    const int n = n0 + wv * 16 + lr;
    const float bval = bias[n];
#pragma unroll
    for (int mt = 0; mt < 4; ++mt) {
#pragma unroll
        for (int i = 0; i < 4; ++i) {
            int m = m0 + mt * 16 + quad * 4 + i;
            C[(size_t)m * H_DIM + n] = (f16)(acc[mt][i] + bval);
        }
    }
}

// --------------------------- 3-role scan, self-contained WGs ---------------
// grid = 16 x 512 threads (8 waves), 1 WG/CU (144KB LDS).
// bid 0-3:  L0    r=bid       16 rows x 512 cols, h in LDS stage.
// bid 4-7:  L1REC r=bid-4     same, input z from hexZ.
// bid 8-15: PROJ  r=(bid-8)>>1, half=(bid-8)&1  (256 cols, W all-register).
// hex0 [8][64][128] u64, hexZ [8][4][2][2048] u64 (pos 1024 ++ neg 1024).
// progP[r*2+half]: PROJ consumed h0_t -> t+1. progL[r]: L1REC consumed z_t.
__global__ __launch_bounds__(512, 1)
void rnn_scan3(const f16* __restrict__ pre0,    // [B,Tc,H] chunk-local
               const f16* __restrict__ Whh0,    // [H,H] fp16
               const f16* __restrict__ Wih1,    // [H,H] fp16
               const f16* __restrict__ Whh1,    // [H,H] fp16
               const float* __restrict__ bias1, // [H] fp32
               u64* __restrict__ hex0,          // [8][64][128]
               u64* __restrict__ hexZ,          // [8][4][2][2048]
               f16* __restrict__ hc0,           // [B,H] layer-0 carry
               f16* __restrict__ hc1,           // [B,H] layer-1 carry
               u32* __restrict__ progP,         // [8]
               u32* __restrict__ progL,         // [4]
               int t0, int Tc,
               float* __restrict__ h_last)      // [B,H] fp32
{
    __shared__ f16 stage[16 * 512];    // 16KB: h (L0/L1REC) or sH0 (PROJ)
    __shared__ f16 WL[128 * 512];      // 128KB: 4th W j-block (recurrent only)
    const int bid = blockIdx.x;
    const int tid = threadIdx.x;
    const int w = tid >> 6, lane = tid & 63;
    const int lr = lane & 15, quad = lane >> 4;

    if (bid >= 8) {
        // ============================ PROJ ============================
        const int r = (bid - 8) >> 1, half = (bid - 8) & 1;
        const int rows0 = r * 16;
        const int c0p = half * 256 + w * 32;
        half8 Bf[2][16];
#pragma unroll
        for (int j = 0; j < 2; ++j)
#pragma unroll
            for (int kc = 0; kc < 16; ++kc)
                Bf[j][kc] = *(const half8*)(Wih1 + (size_t)(c0p + j * 16 + lr) * H_DIM
                                            + kc * 32 + quad * 8);
        float bvv[2] = { bias1[c0p + lr], bias1[c0p + 16 + lr] };
        const int rrow = tid >> 5;               // 16 rows x 32 thr
        const int rc4 = (tid & 31) * 4;          // 4 u64-cols per thread
        int hidx[4];
#pragma unroll
        for (int q = 0; q < 4; ++q) hidx[q] = rc4 + q;
        const int lc0 = w * 32 + lr, lc1 = lc0 + 16;

        u64 vv[4];
        {
            u64* src = hex0 + ((size_t)(t0 & 7) * 64 + rows0 + rrow) * 128;
#pragma unroll
            for (int q = 0; q < 4; ++q) vv[q] = aload(&src[hidx[q]]);
        }

        for (int tt = 0; tt < Tc; ++tt) {
            const int t = t0 + tt;
            const int nb = t & 7;
            const u64 em = tagmask(t);
            const int need = t - LAG;
            const u32 want = (u32)(need + 1);

            u32 plv = 0xffffffffu;
            if (need >= 0) plv = aload32(&progL[r]);   // early poll

            // validate h0_t -> stage (sH0)
            {
                u64* src = hex0 + ((size_t)nb * 64 + rows0 + rrow) * 128;
                validateN<4>(src, hidx, em, vv);
#pragma unroll
                for (int q = 0; q < 4; ++q) {
                    int cu = rc4 + q;
                    *(u64*)&stage[rrow * 512 + ((cu >> 1) ^ (rrow & 7)) * 8 + (cu & 1) * 4] =
                        vv[q] & VMASK;
                }
            }
            __syncthreads();   // sH0 ready; all hex0[t] reads done
            if (tid == 0) astore32(&progP[r * 2 + half], (u32)(t + 1));

            float4v acc0 = {0.f,0.f,0.f,0.f}, acc1 = {0.f,0.f,0.f,0.f};
#pragma unroll
            for (int kc = 0; kc < 16; ++kc) {
                half8 a = *(const half8*)&stage[lr * 512 + (((kc * 4 + quad) ^ (lr & 7)) * 8)];
                acc0 = __builtin_amdgcn_mfma_f32_16x16x32_f16(a, Bf[0][kc], acc0, 0, 0, 0);
                acc1 = __builtin_amdgcn_mfma_f32_16x16x32_f16(a, Bf[1][kc], acc1, 0, 0, 0);
            }

            // pack z = acc + bias as pos/neg col-major u64 (4 rows per u64)
            u64 zw[4];
#pragma unroll
            for (int j = 0; j < 2; ++j) {
                const float4v& a = j ? acc1 : acc0;
                u64 wp = 0, wn = 0;
#pragma unroll
                for (int i = 0; i < 4; ++i) {
                    float z = a[i] + bvv[j];
                    union { f16 h; u16 u; } cp, cn;
                    cp.h = (f16)fmaxf(z, 0.f);
                    cn.h = (f16)fmaxf(-z, 0.f);
                    wp |= ((u64)cp.u) << (16 * i);
                    wn |= ((u64)cn.u) << (16 * i);
                }
                zw[j] = wp; zw[2 + j] = wn;
            }

            // throttle: publishing z_t destroys z_{t-8}; progL >= t-6 ok.
            if (need >= 0) {
                int g = 0;
                while (plv < want && g < SPIN_LIM) { plv = aload32(&progL[r]); ++g; }
            }

            {
                u64* dz = hexZ + (((size_t)nb * 4 + r) * 2 + half) * 2048;
                astore(&dz[lc0 * 4 + quad],        zw[0] | em);
                astore(&dz[lc1 * 4 + quad],        zw[1] | em);
                astore(&dz[1024 + lc0 * 4 + quad], zw[2] | em);
                astore(&dz[1024 + lc1 * 4 + quad], zw[3] | em);
            }
            if (tt + 1 < Tc) {
                u64* srcn = hex0 + ((size_t)((t + 1) & 7) * 64 + rows0 + rrow) * 128;
#pragma unroll
                for (int q = 0; q < 4; ++q) vv[q] = aload(&srcn[hidx[q]]);
            }
            __syncthreads();   // protect sH0 rewrite next iteration
        }
        return;
    }

    // ========================= L0 / L1REC =========================
    const int role = bid >> 2;            // 0 = L0, 1 = L1REC
    const int r = bid & 3;
    const int rows0 = r * 16;
    const int c0w = w * 64;               // wave's 64 output cols
    const f16* Wrec = role ? Whh1 : Whh0;
    f16* hcar = role ? hc1 : hc0;

    // W: j-blocks 0..2 in registers (192 VGPR), j-block 3 in LDS (128KB).
    half8 Bf[3][16];
#pragma unroll
    for (int j = 0; j < 3; ++j)
#pragma unroll
        for (int kc = 0; kc < 16; ++kc)
            Bf[j][kc] = *(const half8*)(Wrec + (size_t)(c0w + j * 16 + lr) * H_DIM
                                        + kc * 32 + quad * 8);

    // Fill WL: LDS col cl (0..127) = global col (cl>>4)*64 + 48 + (cl&15);
    // granule-XOR swizzle identical to stage. 512 thr x 16 granules x 16B.
    {
        int cl = tid >> 2, sub = tid & 3;
        int gcol = (cl >> 4) * 64 + 48 + (cl & 15);
        const f16* src = Wrec + (size_t)gcol * H_DIM;
#pragma unroll
        for (int g16 = 0; g16 < 16; ++g16) {
            int g = sub * 16 + g16;
            *(uint4*)&WL[cl * 512 + ((g ^ (cl & 7)) * 8)] =
                *(const uint4*)(src + g * 8);
        }
    }

    if (t0 > 0) {
        int row = tid >> 5, g0 = (tid & 31) * 2;
#pragma unroll
        for (int gq = 0; gq < 2; ++gq) {
            int g = g0 + gq;
            *(uint4*)&stage[row * 512 + ((g ^ (row & 7)) * 8)] =
                *(const uint4*)(hcar + (size_t)(rows0 + row) * H_DIM + g * 8);
        }
    }
    __syncthreads();

    const int wlbase = (w * 16 + lr) * 512;
    const int wlx = (w * 16 + lr) & 7;

    // L1REC z prefetch state
    u64 vvz[8];
    int zidx[8];
    const int halfW = w >> 2, lcw = (w & 3) * 64;
    if (role) {
#pragma unroll
        for (int j = 0; j < 4; ++j) {
            zidx[j] = (lcw + j * 16 + lr) * 4 + quad;
            zidx[4 + j] = 1024 + zidx[j];
        }
        u64* zb = hexZ + (((size_t)(t0 & 7) * 4 + r) * 2 + halfW) * 2048;
#pragma unroll
        for (int q = 0; q < 8; ++q) vvz[q] = aload(&zb[zidx[q]]);
    }

    f16 pvh[4][4];                         // L0: pre_t, pipelined (f16, 8 VGPR)
    if (!role) {
#pragma unroll
        for (int j = 0; j < 4; ++j)
#pragma unroll
            for (int i = 0; i < 4; ++i)
                pvh[j][i] = pre0[((size_t)(rows0 + quad * 4 + i) * Tc + 0) * H_DIM
                                 + c0w + j * 16 + lr];
    }

    const int prow = tid >> 5, pc4 = (tid & 31) * 4;   // L0 publish mapping

    for (int tt = 0; tt < Tc; ++tt) {
        const int t = t0 + tt;
        const int nb = t & 7;
        const u64 em = tagmask(t);
        const int need = t - LAG;
        const u32 want = (u32)(need + 1);

        u32 ppv = 0xffffffffu;
        if (!role && need >= 0 && lane < 2)
            ppv = aload32(&progP[r * 2 + lane]);       // early poll

        // [A] MFMA: h_{t-1} (stage) x [Bf regs | WL LDS block], K=512.
        float4v acc[4] = {{0.f,0.f,0.f,0.f},{0.f,0.f,0.f,0.f},
                          {0.f,0.f,0.f,0.f},{0.f,0.f,0.f,0.f}};
        if (t > 0) {
            half8 wl0 = *(const half8*)&WL[wlbase + (((0 * 4 + quad) ^ wlx) * 8)];
            half8 wl1 = *(const half8*)&WL[wlbase + (((1 * 4 + quad) ^ wlx) * 8)];
#pragma unroll
            for (int kc = 0; kc < 16; ++kc) {
                half8 a = *(const half8*)&stage[lr * 512 + (((kc * 4 + quad) ^ (lr & 7)) * 8)];
                acc[0] = __builtin_amdgcn_mfma_f32_16x16x32_f16(a, Bf[0][kc], acc[0], 0, 0, 0);
                acc[1] = __builtin_amdgcn_mfma_f32_16x16x32_f16(a, Bf[1][kc], acc[1], 0, 0, 0);
                acc[2] = __builtin_amdgcn_mfma_f32_16x16x32_f16(a, Bf[2][kc], acc[2], 0, 0, 0);
                half8 wc = (kc & 1) ? wl1 : wl0;
                acc[3] = __builtin_amdgcn_mfma_f32_16x16x32_f16(a, wc, acc[3], 0, 0, 0);
                if (kc + 2 < 16) {
                    half8 nw = *(const half8*)&WL[wlbase + ((((kc + 2) * 4 + quad) ^ wlx) * 8)];
                    if (kc & 1) wl1 = nw; else wl0 = nw;
                }
            }
        }

        // L1REC: validate z_t (prefetched; PROJ leads -> usually hit).
        if (role) {
            u64* zb = hexZ + (((size_t)nb * 4 + r) * 2 + halfW) * 2048;
            validateN<8>(zb, zidx, em, vvz);
        }
        __syncthreads();   // all stage reads done
        if (role && tid == 0) astore32(&progL[r], (u32)(t + 1));

        // [B] h_t = relu(acc + pv) -> stage (own cols).
        f16 hv[4][4];
#pragma unroll
        for (int j = 0; j < 4; ++j) {
            u64 pw = role ? (vvz[j] & VMASK) : 0ull;
            u64 nw = role ? (vvz[4 + j] & VMASK) : 0ull;
#pragma unroll
            for (int i = 0; i < 4; ++i) {
                float pvv = role ? (f16u((u16)(pw >> (16 * i))) - f16u((u16)(nw >> (16 * i))))
                                 : (float)pvh[j][i];
                float hval = fmaxf(acc[j][i] + pvv, 0.f);
                hv[j][i] = (f16)hval;
                int row = quad * 4 + i, lc = c0w + j * 16 + lr;
                stage[row * 512 + ((lc >> 3) ^ (row & 7)) * 8 + (lc & 7)] = hv[j][i];
            }
        }
        if (role && h_last && t == T_LEN - 1) {
#pragma unroll
            for (int j = 0; j < 4; ++j)
#pragma unroll
                for (int i = 0; i < 4; ++i)
                    h_last[(size_t)(rows0 + quad * 4 + i) * H_DIM + c0w + j * 16 + lr] =
                        (float)hv[j][i];
        }
        if (tt == Tc - 1) {
#pragma unroll
            for (int j = 0; j < 4; ++j)
#pragma unroll
                for (int i = 0; i < 4; ++i)
                    hcar[(size_t)(rows0 + quad * 4 + i) * H_DIM + c0w + j * 16 + lr] =
                        hv[j][i];
        }
        __syncthreads();   // stage (h_t) complete

        // [C] L0: throttle + publish h0_t; both: prefetch next input.
        if (!role) {
            if (need >= 0) {
                bool ok = __all((lane < 2) ? (ppv >= want) : 1);
                int g = 0;
                while (!ok && g < SPIN_LIM) {
                    if (lane < 2) ppv = aload32(&progP[r * 2 + lane]);
                    ok = __all((lane < 2) ? (ppv >= want) : 1);
                    ++g;
                }
            }
            u64* dst = hex0 + ((size_t)nb * 64 + rows0 + prow) * 128;
#pragma unroll
            for (int q = 0; q < 4; ++q) {
                int cu = pc4 + q;
                u64 v = *(const u64*)&stage[prow * 512 + ((cu >> 1) ^ (prow & 7)) * 8
                                            + (cu & 1) * 4];
                astore(&dst[cu], v | em);
            }
            if (tt + 1 < Tc) {
#pragma unroll
                for (int j = 0; j < 4; ++j)
#pragma unroll
                    for (int i = 0; i < 4; ++i)
                        pvh[j][i] = pre0[((size_t)(rows0 + quad * 4 + i) * Tc + tt + 1)
                                         * H_DIM + c0w + j * 16 + lr];
            }
        } else {
            if (tt + 1 < Tc) {
                u64* zb = hexZ + (((size_t)((t + 1) & 7) * 4 + r) * 2 + halfW) * 2048;
#pragma unroll
                for (int q = 0; q < 8; ++q) vvz[q] = aload(&zb[zidx[q]]);
            }
        }
    }
}

// --------------------------- final FC --------------------------------------
__global__ void fc_kernel(const float* __restrict__ hlast, const f16* __restrict__ fcw,
                          const float* __restrict__ fcb, void* __restrict__ out,
                          const int* __restrict__ dtf) {
    int b = blockIdx.x, c = threadIdx.x;
    const float* hrow = hlast + b * H_DIM;
    const f16* wrow = fcw + (size_t)c * H_DIM;
    float s = fcb[c];
    for (int h0 = 0; h0 < H_DIM; h0 += 8) {
        half8 w = *(const half8*)(wrow + h0);
#pragma unroll
        for (int j = 0; j < 8; ++j) s += hrow[h0 + j] * (float)w[j];
    }
    if (*dtf) ((float*)out)[b * 128 + c] = s;
    else      ((u16*)out)[b * 128 + c] = f2bf(s);
}

// --------------------------- launch ----------------------------------------
extern "C" void kernel_launch(void* const* d_in, const int* in_sizes, int n_in,
                              void* d_out, int out_size, void* d_ws, size_t ws_size,
                              hipStream_t stream)
{
    const void* x     = d_in[0];
    const void* W_ih0 = d_in[1];
    const void* W_hh0 = d_in[2];
    const void* b_ih0 = d_in[3];
    const void* b_hh0 = d_in[4];
    const void* W_ih1 = d_in[5];
    const void* W_hh1 = d_in[6];
    const void* b_ih1 = d_in[7];
    const void* b_hh1 = d_in[8];
    const void* fc_w  = d_in[9];
    const void* fc_b  = d_in[10];

    char* ws = (char*)d_ws;
    int*   dtf   = (int*)(ws + 0);            //     64 B
    float* bias0 = (float*)(ws + 4096);       //   2048 B
    float* bias1 = (float*)(ws + 6144);       //   2048 B
    float* fcbf  = (float*)(ws + 8192);       //    512 B
    u32*   progP = (u32*)(ws + 12288);        //    256 B
    u32*   progL = (u32*)(ws + 12544);        //    256 B
    float* hlast = (float*)(ws + 16384);      // 131072 B
    f16*   hc0   = (f16*)(ws + 147456);       //  65536 B
    f16*   hc1   = (f16*)(ws + 212992);       //  65536 B
    u64*   hex0  = (u64*)(ws + 278528);       // 524288 B [8][64][128]
    u64*   hexZ  = (u64*)(ws + 802816);       // 1048576 B [8][4][2][2048]
    f16*   Wih0f = (f16*)(ws + 1851392);      // 262144 B
    f16*   Whh0f = (f16*)(ws + 2113536);      // 524288 B
    f16*   Wih1f = (f16*)(ws + 2637824);      // 524288 B
    f16*   Whh1f = (f16*)(ws + 3162112);      // 524288 B
    f16*   fcwf  = (f16*)(ws + 3686400);      // 131072 B (ends 3817472 < 4MB)

    const size_t misc = 4u << 20;
    int Tc = 128;
    {
        auto need = [&](int tc) {
            return misc + (size_t)B_SZ * (size_t)tc * H_DIM * 2;
        };
        if (ws_size >= need(2048)) Tc = 2048;
        else if (ws_size >= need(1024)) Tc = 1024;
        else if (ws_size >= need(512)) Tc = 512;
        else if (ws_size >= need(256)) Tc = 256;
        else Tc = 128;
    }
    int lgTc = 31 - __builtin_clz((unsigned)Tc);
    f16* bufA = (f16*)(ws + misc);

    detect_kernel<<<dim3(1), dim3(64), 0, stream>>>((const u16*)x, dtf, progP, progL);
    cvt_w_kernel<<<dim3(512), dim3(256), 0, stream>>>(W_ih0, Wih0f, H_DIM * 256, dtf);
    cvt_w_kernel<<<dim3(1024), dim3(256), 0, stream>>>(W_hh0, Whh0f, H_DIM * H_DIM, dtf);
    cvt_w_kernel<<<dim3(1024), dim3(256), 0, stream>>>(W_ih1, Wih1f, H_DIM * H_DIM, dtf);
    cvt_w_kernel<<<dim3(1024), dim3(256), 0, stream>>>(W_hh1, Whh1f, H_DIM * H_DIM, dtf);
    cvt_w_kernel<<<dim3(256), dim3(256), 0, stream>>>(fc_w, fcwf, 128 * H_DIM, dtf);
    bias_kernel<<<dim3(2), dim3(256), 0, stream>>>(b_ih0, b_hh0, bias0, dtf);
    bias_kernel<<<dim3(2), dim3(256), 0, stream>>>(b_ih1, b_hh1, bias1, dtf);
    fcb_kernel<<<dim3(1), dim3(128), 0, stream>>>(fc_b, fcbf, dtf);

    const int NC = T_LEN / Tc;
    const int mblocks = B_SZ * Tc / 64;
    for (int c = 0; c < NC; ++c) {
        const int t0 = c * Tc;
        gemm_tiled<1><<<dim3(mblocks, 8), 256, 0, stream>>>(
            x, Wih0f, bias0, bufA, lgTc, t0, 256, dtf);
        rnn_scan3<<<dim3(16), dim3(512), 0, stream>>>(
            bufA, Whh0f, Wih1f, Whh1f, bias1, hex0, hexZ, hc0, hc1,
            progP, progL, t0, Tc, hlast);
    }
    fc_kernel<<<dim3(B_SZ), dim3(128), 0, stream>>>(hlast, fcwf, fcbf, d_out, dtf);
}